// Round 7
// baseline (1818.349 us; speedup 1.0000x reference)
//
#include <hip/hip_runtime.h>
#include <stdint.h>

// Layered Bayesian net marginal chain: 63 sequential layers, M=16384 nodes,
// K=4 parents, C=16 CPT entries per node.
//
// R5 post-mortem: global dataflow hit 2.13us/layer = the floor for syncing
// through the GLOBAL coherence point (L3): store-visibility + poll-detect
// round trips, 63x sequential. R6 shrinks the coherence domain: within one
// XCD all 32 CUs share one L2, where store->sc0-load visibility is ~10x
// cheaper. Every XCD redundantly computes ALL nodes (8x compute is ~free at
// 6% VALU), syncing purely within its own L2:
//   - producers: normal stores (land in local L2, dirty),
//   - consumers: global_load sc0 (bypass L1, hit shared L2) polling the
//     data-as-flag sentinel,
//   - d_out doubles as 8 independent per-XCD buffers via cache incoherence;
//     all replicas write bitwise-identical values so writeback races are
//     benign, and the kernel-end flush converges them.
// Teams self-organize by HW_REG_XCC_ID + per-XCD tickets (no dependence on
// block->XCD mapping). A one-time all-blocks barrier makes counts final;
// if any XCD got <128 blocks, ALL blocks uniformly run the R5 global path
// (identical arithmetic -> identical output). Poll escalates to agent scope
// after 64 misses (hang-proof valve; agent reads see L2-dirty lines).

namespace {
constexpr int kLayers     = 63;
constexpr int kM          = 16384;
constexpr int kThreads    = 128;              // 2 waves per block
constexpr int kGridBlocks = 2048;             // formation pool: ~256/XCD
constexpr int kTeamBlocks = kM / kThreads;    // 128 member blocks per team
constexpr int kNXCD       = 8;
constexpr float kSentinel = -1.0f;
// d_ws (uint32 words): [x*16] per-XCD tickets (x=0..7), [128] barrier.
}

__global__ void init_kernel(float4* __restrict__ out4, uint32_t* __restrict__ ws) {
  int i = blockIdx.x * blockDim.x + threadIdx.x;   // 262144 = (64 rows*16K)/4
  out4[i] = make_float4(kSentinel, kSentinel, kSentinel, kSentinel);
  if (i < 256) ws[i] = 0u;                         // tickets + barrier
  // normal stores: kernel-end writeback puts sentinels in L3, no dirty
  // copies linger -> chain kernel's sc0 polls fill clean sentinel lines.
}

__device__ __forceinline__ float fsig(float x) {
  return __fdividef(1.0f, 1.0f + __expf(-x));
}

// poll load: local_now -> sc0 (bypass L1, coherent at the XCD-shared L2);
// else agent scope (bypass L1+L2, coherent at L3; reads through dirty L2).
__device__ __forceinline__ float poll_load(const float* p, bool local_now) {
  float v;
  if (local_now) {
    asm volatile("global_load_dword %0, %1, off sc0\n\ts_waitcnt vmcnt(0)"
                 : "=&v"(v) : "v"(p) : "memory");
  } else {
    v = __hip_atomic_load(p, __ATOMIC_RELAXED, __HIP_MEMORY_SCOPE_AGENT);
  }
  return v;
}

template <bool LOCAL>
__device__ __forceinline__ void pub_store(float* p, float v) {
  if (LOCAL) {
    // plain dword store (atomic qualifier stops the compiler caching it);
    // lands in the XCD-local L2 where teammates' sc0 polls see it.
    __hip_atomic_store(p, v, __ATOMIC_RELAXED, __HIP_MEMORY_SCOPE_WORKGROUP);
  } else {
    __hip_atomic_store(p, v, __ATOMIC_RELAXED, __HIP_MEMORY_SCOPE_AGENT);
  }
}

// weight[c] factorizes over parents (MSB-first, matches _configs).
__device__ __forceinline__ float combine16(const float* s,
                                           float p0, float p1, float p2, float p3) {
  float q0 = 1.0f - p0, q1 = 1.0f - p1, q2 = 1.0f - p2, q3 = 1.0f - p3;
  float w0 = q2 * q3, w1 = q2 * p3, w2 = p2 * q3, w3 = p2 * p3;
  float i0 = s[0]  * w0 + s[1]  * w1 + s[2]  * w2 + s[3]  * w3;
  float i1 = s[4]  * w0 + s[5]  * w1 + s[6]  * w2 + s[7]  * w3;
  float i2 = s[8]  * w0 + s[9]  * w1 + s[10] * w2 + s[11] * w3;
  float i3 = s[12] * w0 + s[13] * w1 + s[14] * w2 + s[15] * w3;
  return (q0 * q1) * i0 + (q0 * p1) * i1 + (p0 * q1) * i2 + (p0 * p1) * i3;
}

#define SIG16(S, V0, V1, V2, V3)                                              \
  S[0]  = fsig((V0).x); S[1]  = fsig((V0).y); S[2]  = fsig((V0).z); S[3]  = fsig((V0).w); \
  S[4]  = fsig((V1).x); S[5]  = fsig((V1).y); S[6]  = fsig((V1).z); S[7]  = fsig((V1).w); \
  S[8]  = fsig((V2).x); S[9]  = fsig((V2).y); S[10] = fsig((V2).z); S[11] = fsig((V2).w); \
  S[12] = fsig((V3).x); S[13] = fsig((V3).y); S[14] = fsig((V3).z); S[15] = fsig((V3).w)

template <bool LOCAL>
__device__ __forceinline__ void run_chain(int slot,
    const float* __restrict__ root_logits, const float4* __restrict__ lg,
    const int4* __restrict__ pidx, float* __restrict__ out)
{
  const int m = slot * kThreads + (int)threadIdx.x;

  pub_store<LOCAL>(&out[m], fsig(root_logits[m]));

  int4   idx = pidx[m];
  float4 l0 = lg[(size_t)m * 4 + 0], l1 = lg[(size_t)m * 4 + 1];
  float4 l2 = lg[(size_t)m * 4 + 2], l3 = lg[(size_t)m * 4 + 3];

  const float* prev = out;
  float*       cur  = out + kM;

  for (int t = 0; ; ) {
    // prefetch next layer's statics (normal cached loads, fly during poll)
    const int tn = (t + 1 < kLayers) ? t + 1 : t;
    const size_t bn = (size_t)tn * kM + m;
    int4   idxn = pidx[bn];
    float4 n0 = lg[bn * 4 + 0], n1 = lg[bn * 4 + 1];
    float4 n2 = lg[bn * 4 + 2], n3 = lg[bn * 4 + 3];

    float s[16]; SIG16(s, l0, l1, l2, l3);

    // ---- data-as-flag wait on the 4 parents ----
    const float* a0 = &prev[idx.x];
    const float* a1 = &prev[idx.y];
    const float* a2 = &prev[idx.z];
    const float* a3 = &prev[idx.w];
    float p0 = poll_load(a0, LOCAL);
    float p1 = poll_load(a1, LOCAL);
    float p2 = poll_load(a2, LOCAL);
    float p3 = poll_load(a3, LOCAL);
    int tries = 0;
    while (__any((p0 < 0.0f) | (p1 < 0.0f) | (p2 < 0.0f) | (p3 < 0.0f))) {
      __builtin_amdgcn_s_sleep(2);
      // escalate to agent scope after 64 misses (non-sticky): hang-proof
      // even if sc0 semantics differ; agent reads see L2-dirty lines.
      const bool ln = LOCAL && (++tries < 64);
      if (p0 < 0.0f) p0 = poll_load(a0, ln);
      if (p1 < 0.0f) p1 = poll_load(a1, ln);
      if (p2 < 0.0f) p2 = poll_load(a2, ln);
      if (p3 < 0.0f) p3 = poll_load(a3, ln);
    }

    pub_store<LOCAL>(&cur[m], combine16(s, p0, p1, p2, p3));

    if (++t == kLayers) break;
    prev = cur; cur += kM;
    idx = idxn; l0 = n0; l1 = n1; l2 = n2; l3 = n3;
  }
}

__global__ __launch_bounds__(kThreads) void bayes_chain_kernel(
    const float* __restrict__ root_logits,   // [kM]
    const float* __restrict__ layer_logits,  // [kLayers][kM][16]
    const int*   __restrict__ parent_idx,    // [kLayers][kM][4]
    float* __restrict__ out,                 // [kLayers+1][kM]
    uint32_t* __restrict__ ws)
{
  __shared__ int sh_rank, sh_fast;

  if (threadIdx.x == 0) {
    unsigned xcc;
    asm volatile("s_getreg_b32 %0, hwreg(HW_REG_XCC_ID)" : "=s"(xcc));
    xcc &= 7u;
    unsigned r = __hip_atomic_fetch_add(&ws[xcc * 16], 1u,
                                        __ATOMIC_RELAXED, __HIP_MEMORY_SCOPE_AGENT);
    // ticket response received => count updated at L3 before we arrive
    asm volatile("s_waitcnt vmcnt(0)" ::: "memory");
    __hip_atomic_fetch_add(&ws[128], 1u,
                           __ATOMIC_RELAXED, __HIP_MEMORY_SCOPE_AGENT);
    // formation barrier: counts are final once all blocks arrived
    while (__hip_atomic_load(&ws[128], __ATOMIC_RELAXED,
                             __HIP_MEMORY_SCOPE_AGENT) < (unsigned)gridDim.x) {
      __builtin_amdgcn_s_sleep(8);
    }
    int ok = 1;
    for (int x = 0; x < kNXCD; ++x) {
      unsigned c = __hip_atomic_load(&ws[x * 16], __ATOMIC_RELAXED,
                                     __HIP_MEMORY_SCOPE_AGENT);
      ok &= (c >= (unsigned)kTeamBlocks);
    }
    sh_rank = (int)r;
    sh_fast = ok;   // identical decision in every block (counts final)
  }
  __syncthreads();
  const int rank = sh_rank;
  const int fast = sh_fast;

  const int4*   pidx = reinterpret_cast<const int4*>(parent_idx);
  const float4* lg   = reinterpret_cast<const float4*>(layer_logits);

  if (fast) {
    // XCD-local replica: first kTeamBlocks ranks per XCD cover all nodes
    if (rank >= kTeamBlocks) return;
    run_chain<true>(rank, root_logits, lg, pidx, out);
  } else {
    // global fallback (R5 semantics, identical arithmetic)
    if ((int)blockIdx.x >= kTeamBlocks) return;
    run_chain<false>((int)blockIdx.x, root_logits, lg, pidx, out);
  }
}

extern "C" void kernel_launch(void* const* d_in, const int* in_sizes, int n_in,
                              void* d_out, int out_size, void* d_ws, size_t ws_size,
                              hipStream_t stream) {
  const float* root = (const float*)d_in[0];
  const float* lg   = (const float*)d_in[1];
  const int*   pidx = (const int*)d_in[2];
  float* out        = (float*)d_out;
  uint32_t* ws      = (uint32_t*)d_ws;   // 1KB used

  // re-init sentinels + tickets/barrier every launch (graph replays don't
  // re-poison; previous replay's leftovers would wreck ranking/dataflow).
  init_kernel<<<1024, 256, 0, stream>>>((float4*)out, ws);

  bayes_chain_kernel<<<kGridBlocks, kThreads, 0, stream>>>(root, lg, pidx, out, ws);
}

// Round 8
// 145.488 us; speedup vs baseline: 12.4983x; 12.4983x over previous
//
#include <hip/hip_runtime.h>
#include <stdint.h>

// Layered Bayesian net marginal chain: 63 sequential layers, M=16384 nodes,
// K=4 parents, C=16 CPT entries per node.
//
// R6 post-mortem: XCD-replication regressed 13.6x (FETCH 65->340MB; 8x
// redundant input streaming not absorbed by L3, blocks spun at 25% occ).
// Reverted to the R5 global-dataflow structure (134us, best so far).
//
// R5 -> R7 (same structure, detect-side surgery):
//   - data-as-flag sync unchanged: sentinel-init rows, write-through
//     relaxed AGENT-scope stores, consumers poll their own 4 parents,
//   - poll loads issued BEFORE the static sigmoid burst (first L3 RTT
//     hides under ~130 VALU cycles),
//   - hard spin, no s_sleep (kills detection quantization),
//   - per-lane predicated re-poll: only parents still missing are
//     reloaded (cuts steady-state poll traffic ~4x, deflating the L3
//     contention that inflates the globally-coupled pace).

namespace {
constexpr int kLayers  = 63;      // hidden layers
constexpr int kM       = 16384;   // nodes per layer
constexpr int kBlocks  = 256;     // 1 block (1 wave) per CU
constexpr int kThreads = 64;      // kBlocks*kThreads == kM, 1 thread per node
constexpr float kSentinel = -1.0f;
}

// Re-init the whole out buffer (rows 0..63) to sentinel each launch.
// Normal cached stores; kernel-end writeback makes them visible to the
// chain kernel's agent-scope (L2-bypassing) polls.
__global__ void init_sentinel_kernel(float4* __restrict__ out4) {
  int i = blockIdx.x * blockDim.x + threadIdx.x;   // 262144 float4 total
  out4[i] = make_float4(kSentinel, kSentinel, kSentinel, kSentinel);
}

__device__ __forceinline__ float fsig(float x) {
  // sigmoid; fp32 fast-math is far inside the 1.8e-2 abs threshold
  return __fdividef(1.0f, 1.0f + __expf(-x));
}

// Agent-scope (device-coherent) accesses: bypass the non-coherent per-XCD
// L1/L2, hit the coherence point directly. No cache-wide maintenance.
__device__ __forceinline__ void agent_store(float* p, float v) {
  __hip_atomic_store(p, v, __ATOMIC_RELAXED, __HIP_MEMORY_SCOPE_AGENT);
}
__device__ __forceinline__ float agent_load(const float* p) {
  return __hip_atomic_load(p, __ATOMIC_RELAXED, __HIP_MEMORY_SCOPE_AGENT);
}

// weight[c] factorizes over parents (MSB-first bit order, matches _configs):
// c = b0 b1 b2 b3, fk(1)=pk, fk(0)=1-pk.
__device__ __forceinline__ float combine16(const float* s,
                                           float p0, float p1, float p2, float p3) {
  float q0 = 1.0f - p0, q1 = 1.0f - p1, q2 = 1.0f - p2, q3 = 1.0f - p3;
  float w0 = q2 * q3, w1 = q2 * p3, w2 = p2 * q3, w3 = p2 * p3;   // (b2,b3)
  float i0 = s[0]  * w0 + s[1]  * w1 + s[2]  * w2 + s[3]  * w3;   // (b0,b1)=(0,0)
  float i1 = s[4]  * w0 + s[5]  * w1 + s[6]  * w2 + s[7]  * w3;   // (0,1)
  float i2 = s[8]  * w0 + s[9]  * w1 + s[10] * w2 + s[11] * w3;   // (1,0)
  float i3 = s[12] * w0 + s[13] * w1 + s[14] * w2 + s[15] * w3;   // (1,1)
  return (q0 * q1) * i0 + (q0 * p1) * i1 + (p0 * q1) * i2 + (p0 * p1) * i3;
}

#define SIG16(S, V0, V1, V2, V3)                                              \
  S[0]  = fsig((V0).x); S[1]  = fsig((V0).y); S[2]  = fsig((V0).z); S[3]  = fsig((V0).w); \
  S[4]  = fsig((V1).x); S[5]  = fsig((V1).y); S[6]  = fsig((V1).z); S[7]  = fsig((V1).w); \
  S[8]  = fsig((V2).x); S[9]  = fsig((V2).y); S[10] = fsig((V2).z); S[11] = fsig((V2).w); \
  S[12] = fsig((V3).x); S[13] = fsig((V3).y); S[14] = fsig((V3).z); S[15] = fsig((V3).w)

__global__ __launch_bounds__(kThreads, 1) void bayes_chain_kernel(
    const float* __restrict__ root_logits,   // [kM]
    const float* __restrict__ layer_logits,  // [kLayers][kM][16]
    const int*   __restrict__ parent_idx,    // [kLayers][kM][4]
    float* __restrict__ out)                 // [kLayers+1][kM]
{
  const int m = blockIdx.x * kThreads + threadIdx.x;

  const int4*   pidx = reinterpret_cast<const int4*>(parent_idx);     // [63][M]
  const float4* lg   = reinterpret_cast<const float4*>(layer_logits); // [63][M][4]

  // ---- row 0: root marginals, write-through so consumers' polls see them ----
  agent_store(&out[m], fsig(root_logits[m]));

  // prefetch layer 0 statics
  int4   idx = pidx[m];
  float4 l0 = lg[(size_t)m * 4 + 0], l1 = lg[(size_t)m * 4 + 1];
  float4 l2 = lg[(size_t)m * 4 + 2], l3 = lg[(size_t)m * 4 + 3];

  const float* prev = out;
  float*       cur  = out + kM;

  for (int t = 0; ; ) {
    // issue the first parent poll IMMEDIATELY (its L3 round-trip overlaps
    // the static prefetch + sigmoid VALU burst below)
    const float* a0 = &prev[idx.x];
    const float* a1 = &prev[idx.y];
    const float* a2 = &prev[idx.z];
    const float* a3 = &prev[idx.w];
    float p0 = agent_load(a0);
    float p1 = agent_load(a1);
    float p2 = agent_load(a2);
    float p3 = agent_load(a3);

    // prefetch next layer's statics (coalesced, in flight during the poll)
    const int tn = (t + 1 < kLayers) ? t + 1 : t;   // clamp: harmless reload
    const size_t bn = (size_t)tn * kM + m;
    int4   idxn = pidx[bn];
    float4 n0 = lg[bn * 4 + 0], n1 = lg[bn * 4 + 1];
    float4 n2 = lg[bn * 4 + 2], n3 = lg[bn * 4 + 3];

    // static sigmoids for THIS layer (pure VALU, hides the first poll RTT)
    float s[16]; SIG16(s, l0, l1, l2, l3);

    // ---- dataflow wait: hard spin, re-poll ONLY missing parents ----
    for (;;) {
      bool need0 = p0 < 0.0f, need1 = p1 < 0.0f;
      bool need2 = p2 < 0.0f, need3 = p3 < 0.0f;
      if (!__any(need0 | need1 | need2 | need3)) break;
      if (need0) p0 = agent_load(a0);
      if (need1) p1 = agent_load(a1);
      if (need2) p2 = agent_load(a2);
      if (need3) p3 = agent_load(a3);
    }

    // combine + publish (write-through: this IS the ready-flag for layer t+1)
    agent_store(&cur[m], combine16(s, p0, p1, p2, p3));

    if (++t == kLayers) break;
    prev = cur;
    cur += kM;
    idx = idxn;
    l0 = n0; l1 = n1; l2 = n2; l3 = n3;
  }
}

extern "C" void kernel_launch(void* const* d_in, const int* in_sizes, int n_in,
                              void* d_out, int out_size, void* d_ws, size_t ws_size,
                              hipStream_t stream) {
  const float* root = (const float*)d_in[0];
  const float* lg   = (const float*)d_in[1];
  const int*   pidx = (const int*)d_in[2];
  float* out        = (float*)d_out;

  // (kLayers+1)*kM floats = 262144 float4 -> sentinel every launch
  // (harness poisons d_out once but never between graph replays; stale
  // positive values from the previous replay would be read as ready).
  init_sentinel_kernel<<<1024, 256, 0, stream>>>((float4*)out);

  bayes_chain_kernel<<<kBlocks, kThreads, 0, stream>>>(root, lg, pidx, out);
}

// Round 9
// 136.925 us; speedup vs baseline: 13.2799x; 1.0625x over previous
//
#include <hip/hip_runtime.h>
#include <stdint.h>

// Layered Bayesian net marginal chain: 63 sequential layers, M=16384 nodes,
// K=4 parents, C=16 CPT entries per node.
//
// Structure (R5, best=134us): global fine-grained dataflow. Marginals are
// strictly positive, so the DATA is its own ready-flag: sentinel-init rows,
// relaxed AGENT-scope write-through stores, consumers poll their own 4
// parent slots until nonnegative. No barriers, no fences.
//
// R7 post-mortem: poll-traffic reduction did nothing -> contention is not
// the limiter. New model: vmcnt ENTANGLEMENT. vmcnt retires loads in issue
// order (learn_hip m135), so the spin's first check (compiler emits a wait
// covering the polls) also retired the 5 same-iteration HBM prefetch loads
// (~0.9us + tail). With 256-random-parent coupling, each layer paces at the
// MAX over waves of that HBM tail => 2.2us/layer.
//
// R8 fix: queue-position control. Issue polls FIRST (oldest), sched_barrier,
// then the 5 prefetch loads (newer), sched_barrier, then sigmoids, then a
// ROTATED fast-path check so the compiler waits vmcnt(5) = polls only; the
// HBM prefetch stays in flight and ages a full layer before its consumer
// (next iteration's SIG16) needs it. Only late-parent waves enter the
// reload loop whose vmcnt(0) drags the prefetch once (overlapped with the
// parent wait anyway).

namespace {
constexpr int kLayers  = 63;      // hidden layers
constexpr int kM       = 16384;   // nodes per layer
constexpr int kBlocks  = 256;     // 1 block (1 wave) per CU
constexpr int kThreads = 64;      // kBlocks*kThreads == kM, 1 thread per node
constexpr float kSentinel = -1.0f;
}

// Re-init the whole out buffer (rows 0..63) to sentinel each launch.
// Normal cached stores; kernel-end writeback makes them visible to the
// chain kernel's agent-scope (cache-bypassing) polls.
__global__ void init_sentinel_kernel(float4* __restrict__ out4) {
  int i = blockIdx.x * blockDim.x + threadIdx.x;   // 262144 float4 total
  out4[i] = make_float4(kSentinel, kSentinel, kSentinel, kSentinel);
}

__device__ __forceinline__ float fsig(float x) {
  // sigmoid; fp32 fast-math is far inside the 1.8e-2 abs threshold
  return __fdividef(1.0f, 1.0f + __expf(-x));
}

// Agent-scope (device-coherent) accesses: bypass the non-coherent per-XCD
// L1/L2, hit the coherence point directly. No cache-wide maintenance.
__device__ __forceinline__ void agent_store(float* p, float v) {
  __hip_atomic_store(p, v, __ATOMIC_RELAXED, __HIP_MEMORY_SCOPE_AGENT);
}
__device__ __forceinline__ float agent_load(const float* p) {
  return __hip_atomic_load(p, __ATOMIC_RELAXED, __HIP_MEMORY_SCOPE_AGENT);
}

// weight[c] factorizes over parents (MSB-first bit order, matches _configs):
// c = b0 b1 b2 b3, fk(1)=pk, fk(0)=1-pk.
__device__ __forceinline__ float combine16(const float* s,
                                           float p0, float p1, float p2, float p3) {
  float q0 = 1.0f - p0, q1 = 1.0f - p1, q2 = 1.0f - p2, q3 = 1.0f - p3;
  float w0 = q2 * q3, w1 = q2 * p3, w2 = p2 * q3, w3 = p2 * p3;   // (b2,b3)
  float i0 = s[0]  * w0 + s[1]  * w1 + s[2]  * w2 + s[3]  * w3;   // (b0,b1)=(0,0)
  float i1 = s[4]  * w0 + s[5]  * w1 + s[6]  * w2 + s[7]  * w3;   // (0,1)
  float i2 = s[8]  * w0 + s[9]  * w1 + s[10] * w2 + s[11] * w3;   // (1,0)
  float i3 = s[12] * w0 + s[13] * w1 + s[14] * w2 + s[15] * w3;   // (1,1)
  return (q0 * q1) * i0 + (q0 * p1) * i1 + (p0 * q1) * i2 + (p0 * p1) * i3;
}

#define SIG16(S, V0, V1, V2, V3)                                              \
  S[0]  = fsig((V0).x); S[1]  = fsig((V0).y); S[2]  = fsig((V0).z); S[3]  = fsig((V0).w); \
  S[4]  = fsig((V1).x); S[5]  = fsig((V1).y); S[6]  = fsig((V1).z); S[7]  = fsig((V1).w); \
  S[8]  = fsig((V2).x); S[9]  = fsig((V2).y); S[10] = fsig((V2).z); S[11] = fsig((V2).w); \
  S[12] = fsig((V3).x); S[13] = fsig((V3).y); S[14] = fsig((V3).z); S[15] = fsig((V3).w)

__global__ __launch_bounds__(kThreads, 1) void bayes_chain_kernel(
    const float* __restrict__ root_logits,   // [kM]
    const float* __restrict__ layer_logits,  // [kLayers][kM][16]
    const int*   __restrict__ parent_idx,    // [kLayers][kM][4]
    float* __restrict__ out)                 // [kLayers+1][kM]
{
  const int m = blockIdx.x * kThreads + threadIdx.x;

  const int4*   pidx = reinterpret_cast<const int4*>(parent_idx);     // [63][M]
  const float4* lg   = reinterpret_cast<const float4*>(layer_logits); // [63][M][4]

  // ---- row 0: root marginals, write-through so consumers' polls see them ----
  agent_store(&out[m], fsig(root_logits[m]));

  // statics for layer 0 (normal cached loads)
  int4   idx = pidx[m];
  float4 l0 = lg[(size_t)m * 4 + 0], l1 = lg[(size_t)m * 4 + 1];
  float4 l2 = lg[(size_t)m * 4 + 2], l3 = lg[(size_t)m * 4 + 3];

  const float* prev = out;
  float*       cur  = out + kM;

  for (int t = 0; ; ) {
    // ---- 1. poll loads FIRST: oldest slots in the in-order vmcnt queue ----
    const float* a0 = &prev[idx.x];
    const float* a1 = &prev[idx.y];
    const float* a2 = &prev[idx.z];
    const float* a3 = &prev[idx.w];
    float p0 = agent_load(a0);
    float p1 = agent_load(a1);
    float p2 = agent_load(a2);
    float p3 = agent_load(a3);
    __builtin_amdgcn_sched_barrier(0);   // pin: polls issued before prefetch

    // ---- 2. HBM prefetch of next layer's statics (5 loads, NEWER) ----
    // Consumed only next iteration (aged a full layer ~ fully hidden).
    const int tn = (t + 1 < kLayers) ? t + 1 : t;   // clamp: harmless reload
    const size_t bn = (size_t)tn * kM + m;
    int4   idxn = pidx[bn];
    float4 n0 = lg[bn * 4 + 0], n1 = lg[bn * 4 + 1];
    float4 n2 = lg[bn * 4 + 2], n3 = lg[bn * 4 + 3];
    __builtin_amdgcn_sched_barrier(0);   // pin: prefetch issued before VALU

    // ---- 3. static sigmoids (pure VALU, runs while the polls fly) ----
    float s[16]; SIG16(s, l0, l1, l2, l3);

    // ---- 4. rotated dataflow wait ----
    // Fast path: the compiler's wait for p0..p3 here is vmcnt(5) — the 4
    // OLDEST (polls) retire, the 5 prefetch loads stay in flight. Only a
    // genuinely-late wave enters the reload loop (whose waits drag the
    // prefetch once, overlapped with the parent wait).
    if ((p0 < 0.0f) | (p1 < 0.0f) | (p2 < 0.0f) | (p3 < 0.0f)) {
      do {
        p0 = agent_load(a0);
        p1 = agent_load(a1);
        p2 = agent_load(a2);
        p3 = agent_load(a3);
      } while ((p0 < 0.0f) | (p1 < 0.0f) | (p2 < 0.0f) | (p3 < 0.0f));
    }

    // ---- 5. combine + publish (store IS the ready-flag for layer t+1) ----
    agent_store(&cur[m], combine16(s, p0, p1, p2, p3));

    if (++t == kLayers) break;
    prev = cur;
    cur += kM;
    idx = idxn;
    l0 = n0; l1 = n1; l2 = n2; l3 = n3;
  }
}

extern "C" void kernel_launch(void* const* d_in, const int* in_sizes, int n_in,
                              void* d_out, int out_size, void* d_ws, size_t ws_size,
                              hipStream_t stream) {
  const float* root = (const float*)d_in[0];
  const float* lg   = (const float*)d_in[1];
  const int*   pidx = (const int*)d_in[2];
  float* out        = (float*)d_out;

  // (kLayers+1)*kM floats = 262144 float4 -> sentinel every launch
  // (harness poisons d_out once but never between graph replays; stale
  // positive values from the previous replay would be read as ready).
  init_sentinel_kernel<<<1024, 256, 0, stream>>>((float4*)out);

  bayes_chain_kernel<<<kBlocks, kThreads, 0, stream>>>(root, lg, pidx, out);
}

// Round 10
// 122.907 us; speedup vs baseline: 14.7945x; 1.1141x over previous
//
#include <hip/hip_runtime.h>
#include <stdint.h>

// Layered Bayesian net marginal chain: 63 sequential layers, M=16384 nodes,
// K=4 parents, C=16 CPT entries per node.
//
// Structure (R5, best=134us): global fine-grained dataflow. Marginals are
// strictly positive, so the DATA is its own ready-flag: sentinel-init rows,
// relaxed AGENT-scope write-through stores, consumers poll their own 4
// parent slots until nonnegative. No barriers, no fences.
//
// R8 post-mortem: rotated check was null because it fixed only the rare
// fast path; critical-path waves live in the SPIN, whose first reload still
// drags the HBM prefetch (in-order vmcnt retirement) and whose cadence is a
// full poll RTT (issue->wait(0)->check->reissue).
//
// R9: manual staggered polling, clean queue.
//  - spin uses inline-asm global_load sc0 sc1 (agent read-through) into TWO
//    alternating 4-reg batches with hand-placed s_waitcnt vmcnt(4): check
//    cadence ~RTT/2, and no check ever waits on prefetch/store.
//  - prefetch of next layer statics moved AFTER the publish store; its
//    compiler-emitted wait drains BEFORE the spin (pinned by sched_barrier),
//    so the spin's vmcnt queue holds polls only.
//  - monotonic slots (sentinel -> final, single write) make racy register
//    reads safe: any >=0 observed is the true final value.
//  - 512-try escalation valve -> proven __hip_atomic_load loop (hang-proof
//    if sc0 sc1 flag semantics surprise).

namespace {
constexpr int kLayers  = 63;      // hidden layers
constexpr int kM       = 16384;   // nodes per layer
constexpr int kBlocks  = 256;     // 1 block (1 wave) per CU
constexpr int kThreads = 64;      // kBlocks*kThreads == kM, 1 thread per node
constexpr float kSentinel = -1.0f;
}

// Re-init the whole out buffer (rows 0..63) to sentinel each launch.
// Normal cached stores; kernel-end writeback makes them visible to the
// chain kernel's agent-scope (cache-bypassing) polls.
__global__ void init_sentinel_kernel(float4* __restrict__ out4) {
  int i = blockIdx.x * blockDim.x + threadIdx.x;   // 262144 float4 total
  out4[i] = make_float4(kSentinel, kSentinel, kSentinel, kSentinel);
}

__device__ __forceinline__ float fsig(float x) {
  // sigmoid; fp32 fast-math is far inside the 1.8e-2 abs threshold
  return __fdividef(1.0f, 1.0f + __expf(-x));
}

// Agent-scope (device-coherent) accesses: bypass the non-coherent per-XCD
// L1/L2, hit the coherence point directly. No cache-wide maintenance.
__device__ __forceinline__ void agent_store(float* p, float v) {
  __hip_atomic_store(p, v, __ATOMIC_RELAXED, __HIP_MEMORY_SCOPE_AGENT);
}
__device__ __forceinline__ float agent_load(const float* p) {
  return __hip_atomic_load(p, __ATOMIC_RELAXED, __HIP_MEMORY_SCOPE_AGENT);
}

// Issue 4 agent read-through polls as raw asm: WE own the waitcnt for these
// (the compiler cannot see them), giving exact control of check cadence.
#define POLL_ISSUE4(r0, r1, r2, r3, A0, A1, A2, A3)                         \
  asm volatile("global_load_dword %0, %4, off sc0 sc1\n\t"                  \
               "global_load_dword %1, %5, off sc0 sc1\n\t"                  \
               "global_load_dword %2, %6, off sc0 sc1\n\t"                  \
               "global_load_dword %3, %7, off sc0 sc1"                      \
               : "=&v"(r0), "=&v"(r1), "=&v"(r2), "=&v"(r3)                 \
               : "v"(A0), "v"(A1), "v"(A2), "v"(A3)                         \
               : "memory")

// weight[c] factorizes over parents (MSB-first bit order, matches _configs):
// c = b0 b1 b2 b3, fk(1)=pk, fk(0)=1-pk.
__device__ __forceinline__ float combine16(const float* s,
                                           float p0, float p1, float p2, float p3) {
  float q0 = 1.0f - p0, q1 = 1.0f - p1, q2 = 1.0f - p2, q3 = 1.0f - p3;
  float w0 = q2 * q3, w1 = q2 * p3, w2 = p2 * q3, w3 = p2 * p3;   // (b2,b3)
  float i0 = s[0]  * w0 + s[1]  * w1 + s[2]  * w2 + s[3]  * w3;   // (b0,b1)=(0,0)
  float i1 = s[4]  * w0 + s[5]  * w1 + s[6]  * w2 + s[7]  * w3;   // (0,1)
  float i2 = s[8]  * w0 + s[9]  * w1 + s[10] * w2 + s[11] * w3;   // (1,0)
  float i3 = s[12] * w0 + s[13] * w1 + s[14] * w2 + s[15] * w3;   // (1,1)
  return (q0 * q1) * i0 + (q0 * p1) * i1 + (p0 * q1) * i2 + (p0 * p1) * i3;
}

#define SIG16(S, V0, V1, V2, V3)                                              \
  S[0]  = fsig((V0).x); S[1]  = fsig((V0).y); S[2]  = fsig((V0).z); S[3]  = fsig((V0).w); \
  S[4]  = fsig((V1).x); S[5]  = fsig((V1).y); S[6]  = fsig((V1).z); S[7]  = fsig((V1).w); \
  S[8]  = fsig((V2).x); S[9]  = fsig((V2).y); S[10] = fsig((V2).z); S[11] = fsig((V2).w); \
  S[12] = fsig((V3).x); S[13] = fsig((V3).y); S[14] = fsig((V3).z); S[15] = fsig((V3).w)

__global__ __launch_bounds__(kThreads, 1) void bayes_chain_kernel(
    const float* __restrict__ root_logits,   // [kM]
    const float* __restrict__ layer_logits,  // [kLayers][kM][16]
    const int*   __restrict__ parent_idx,    // [kLayers][kM][4]
    float* __restrict__ out)                 // [kLayers+1][kM]
{
  const int m = blockIdx.x * kThreads + threadIdx.x;

  const int4*   pidx = reinterpret_cast<const int4*>(parent_idx);     // [63][M]
  const float4* lg   = reinterpret_cast<const float4*>(layer_logits); // [63][M][4]

  // ---- row 0: root marginals, write-through so consumers' polls see them ----
  agent_store(&out[m], fsig(root_logits[m]));

  // statics for layer 0 (normal cached loads)
  int4   idx = pidx[m];
  float4 l0 = lg[(size_t)m * 4 + 0], l1 = lg[(size_t)m * 4 + 1];
  float4 l2 = lg[(size_t)m * 4 + 2], l3 = lg[(size_t)m * 4 + 3];

  const float* prev = out;
  float*       cur  = out + kM;

  for (int t = 0; ; ) {
    // ---- pre-spin region (compiler drains prev store + prefetch here) ----
    float s[16]; SIG16(s, l0, l1, l2, l3);
    const float* A0 = &prev[idx.x];
    const float* A1 = &prev[idx.y];
    const float* A2 = &prev[idx.z];
    const float* A3 = &prev[idx.w];
    __builtin_amdgcn_sched_barrier(0);   // pin: nothing sinks into the spin

    // ---- staggered spin: 2 poll batches in flight, cadence ~RTT/2 ----
    float pA0, pA1, pA2, pA3, pB0, pB1, pB2, pB3;
    POLL_ISSUE4(pA0, pA1, pA2, pA3, A0, A1, A2, A3);
    POLL_ISSUE4(pB0, pB1, pB2, pB3, A0, A1, A2, A3);
    float p0 = 0.f, p1 = 0.f, p2 = 0.f, p3 = 0.f;
    bool done = false;
    int tries = 0;
    for (;;) {
      // batch A is the 4 oldest of 8 outstanding -> retire exactly A
      asm volatile("s_waitcnt vmcnt(4)" ::: "memory");
      __builtin_amdgcn_sched_barrier(0);
      if (!done & (pA0 >= 0.f) & (pA1 >= 0.f) & (pA2 >= 0.f) & (pA3 >= 0.f)) {
        p0 = pA0; p1 = pA1; p2 = pA2; p3 = pA3; done = true;
      }
      if (__all(done)) break;
      POLL_ISSUE4(pA0, pA1, pA2, pA3, A0, A1, A2, A3);
      // batch B now oldest
      asm volatile("s_waitcnt vmcnt(4)" ::: "memory");
      __builtin_amdgcn_sched_barrier(0);
      if (!done & (pB0 >= 0.f) & (pB1 >= 0.f) & (pB2 >= 0.f) & (pB3 >= 0.f)) {
        p0 = pB0; p1 = pB1; p2 = pB2; p3 = pB3; done = true;
      }
      if (__all(done)) break;
      if (++tries > 512) {
        // escalation valve: drain manual queue, proven compiler-load loop
        asm volatile("s_waitcnt vmcnt(0)" ::: "memory");
        __builtin_amdgcn_sched_barrier(0);
        while (!__all(done)) {
          float q0 = agent_load(A0), q1 = agent_load(A1);
          float q2 = agent_load(A2), q3 = agent_load(A3);
          if (!done & (q0 >= 0.f) & (q1 >= 0.f) & (q2 >= 0.f) & (q3 >= 0.f)) {
            p0 = q0; p1 = q1; p2 = q2; p3 = q3; done = true;
          }
        }
        break;
      }
      POLL_ISSUE4(pB0, pB1, pB2, pB3, A0, A1, A2, A3);
    }
    __builtin_amdgcn_sched_barrier(0);

    // ---- publish FIRST (this store is the consumers' ready-flag) ----
    agent_store(&cur[m], combine16(s, p0, p1, p2, p3));
    __builtin_amdgcn_sched_barrier(0);

    // ---- then prefetch next layer's statics (aged a full link by use) ----
    const int tn = (t + 1 < kLayers) ? t + 1 : t;   // clamp: harmless reload
    const size_t bn = (size_t)tn * kM + m;
    int4   idxn = pidx[bn];
    float4 n0 = lg[bn * 4 + 0], n1 = lg[bn * 4 + 1];
    float4 n2 = lg[bn * 4 + 2], n3 = lg[bn * 4 + 3];

    if (++t == kLayers) break;
    prev = cur;
    cur += kM;
    idx = idxn;
    l0 = n0; l1 = n1; l2 = n2; l3 = n3;
  }
}

extern "C" void kernel_launch(void* const* d_in, const int* in_sizes, int n_in,
                              void* d_out, int out_size, void* d_ws, size_t ws_size,
                              hipStream_t stream) {
  const float* root = (const float*)d_in[0];
  const float* lg   = (const float*)d_in[1];
  const int*   pidx = (const int*)d_in[2];
  float* out        = (float*)d_out;

  // (kLayers+1)*kM floats = 262144 float4 -> sentinel every launch
  // (harness poisons d_out once but never between graph replays; stale
  // positive values from the previous replay would be read as ready).
  init_sentinel_kernel<<<1024, 256, 0, stream>>>((float4*)out);

  bayes_chain_kernel<<<kBlocks, kThreads, 0, stream>>>(root, lg, pidx, out);
}

// Round 11
// 99.024 us; speedup vs baseline: 18.3627x; 1.2412x over previous
//
#include <hip/hip_runtime.h>
#include <stdint.h>

// Layered Bayesian net marginal chain: 63 sequential layers, M=16384 nodes,
// K=4 parents, C=16 CPT entries per node.
//
// Structure (R5->R9, best=123us): global fine-grained dataflow. Marginals
// are strictly positive, so the DATA is its own ready-flag: sentinel-init
// rows, relaxed AGENT-scope write-through stores, consumers poll their own
// 4 parent slots (inline-asm sc0 sc1 loads, hand-placed vmcnt(4), clean
// queue) until nonnegative. No barriers, no fences.
//
// R9 post-mortem: +12% from de-entangling the spin queue; but the two poll
// batches re-issue back-to-back -> checks cluster, cadence stayed ~RTT.
// Dominant remaining term: WAVE-level coupling — __all(done) over 64 lanes
// x 4 random parents makes each layer-link a max over ~250 producer waves.
//
// R10:
//  1. PER-LANE EARLY PUBLISH: a lane stores its result the moment its own
//     4 parents arrive (inside the spin, under the divergence mask, exactly
//     once). Dependency graph becomes node->4-parents; jitter averages
//     instead of max-accumulating. The interleaved store is swept by the
//     next vmcnt(4), which always leaves exactly the just-issued batch
//     outstanding -> batch-retired invariant holds before every check.
//  2. TRUE RTT/2 STAGGER: s_sleep(8) between the two initial batch issues;
//     the alternating wait/reissue pattern self-sustains the offset.

namespace {
constexpr int kLayers  = 63;      // hidden layers
constexpr int kM       = 16384;   // nodes per layer
constexpr int kBlocks  = 256;     // 1 block (1 wave) per CU
constexpr int kThreads = 64;      // kBlocks*kThreads == kM, 1 thread per node
constexpr float kSentinel = -1.0f;
}

// Re-init the whole out buffer (rows 0..63) to sentinel each launch.
// Normal cached stores; kernel-end writeback makes them visible to the
// chain kernel's agent-scope (cache-bypassing) polls.
__global__ void init_sentinel_kernel(float4* __restrict__ out4) {
  int i = blockIdx.x * blockDim.x + threadIdx.x;   // 262144 float4 total
  out4[i] = make_float4(kSentinel, kSentinel, kSentinel, kSentinel);
}

__device__ __forceinline__ float fsig(float x) {
  // sigmoid; fp32 fast-math is far inside the 1.8e-2 abs threshold
  return __fdividef(1.0f, 1.0f + __expf(-x));
}

// Agent-scope (device-coherent) accesses: bypass the non-coherent per-XCD
// L1/L2, hit the coherence point directly. No cache-wide maintenance.
__device__ __forceinline__ void agent_store(float* p, float v) {
  __hip_atomic_store(p, v, __ATOMIC_RELAXED, __HIP_MEMORY_SCOPE_AGENT);
}
__device__ __forceinline__ float agent_load(const float* p) {
  return __hip_atomic_load(p, __ATOMIC_RELAXED, __HIP_MEMORY_SCOPE_AGENT);
}

// Issue 4 agent read-through polls as raw asm: WE own the waitcnt for these
// (the compiler cannot see them), giving exact control of check cadence.
#define POLL_ISSUE4(r0, r1, r2, r3, A0, A1, A2, A3)                         \
  asm volatile("global_load_dword %0, %4, off sc0 sc1\n\t"                  \
               "global_load_dword %1, %5, off sc0 sc1\n\t"                  \
               "global_load_dword %2, %6, off sc0 sc1\n\t"                  \
               "global_load_dword %3, %7, off sc0 sc1"                      \
               : "=&v"(r0), "=&v"(r1), "=&v"(r2), "=&v"(r3)                 \
               : "v"(A0), "v"(A1), "v"(A2), "v"(A3)                         \
               : "memory")

// weight[c] factorizes over parents (MSB-first bit order, matches _configs):
// c = b0 b1 b2 b3, fk(1)=pk, fk(0)=1-pk.
__device__ __forceinline__ float combine16(const float* s,
                                           float p0, float p1, float p2, float p3) {
  float q0 = 1.0f - p0, q1 = 1.0f - p1, q2 = 1.0f - p2, q3 = 1.0f - p3;
  float w0 = q2 * q3, w1 = q2 * p3, w2 = p2 * q3, w3 = p2 * p3;   // (b2,b3)
  float i0 = s[0]  * w0 + s[1]  * w1 + s[2]  * w2 + s[3]  * w3;   // (b0,b1)=(0,0)
  float i1 = s[4]  * w0 + s[5]  * w1 + s[6]  * w2 + s[7]  * w3;   // (0,1)
  float i2 = s[8]  * w0 + s[9]  * w1 + s[10] * w2 + s[11] * w3;   // (1,0)
  float i3 = s[12] * w0 + s[13] * w1 + s[14] * w2 + s[15] * w3;   // (1,1)
  return (q0 * q1) * i0 + (q0 * p1) * i1 + (p0 * q1) * i2 + (p0 * p1) * i3;
}

#define SIG16(S, V0, V1, V2, V3)                                              \
  S[0]  = fsig((V0).x); S[1]  = fsig((V0).y); S[2]  = fsig((V0).z); S[3]  = fsig((V0).w); \
  S[4]  = fsig((V1).x); S[5]  = fsig((V1).y); S[6]  = fsig((V1).z); S[7]  = fsig((V1).w); \
  S[8]  = fsig((V2).x); S[9]  = fsig((V2).y); S[10] = fsig((V2).z); S[11] = fsig((V2).w); \
  S[12] = fsig((V3).x); S[13] = fsig((V3).y); S[14] = fsig((V3).z); S[15] = fsig((V3).w)

__global__ __launch_bounds__(kThreads, 1) void bayes_chain_kernel(
    const float* __restrict__ root_logits,   // [kM]
    const float* __restrict__ layer_logits,  // [kLayers][kM][16]
    const int*   __restrict__ parent_idx,    // [kLayers][kM][4]
    float* __restrict__ out)                 // [kLayers+1][kM]
{
  const int m = blockIdx.x * kThreads + threadIdx.x;

  const int4*   pidx = reinterpret_cast<const int4*>(parent_idx);     // [63][M]
  const float4* lg   = reinterpret_cast<const float4*>(layer_logits); // [63][M][4]

  // ---- row 0: root marginals, write-through so consumers' polls see them ----
  agent_store(&out[m], fsig(root_logits[m]));

  // statics for layer 0 (normal cached loads)
  int4   idx = pidx[m];
  float4 l0 = lg[(size_t)m * 4 + 0], l1 = lg[(size_t)m * 4 + 1];
  float4 l2 = lg[(size_t)m * 4 + 2], l3 = lg[(size_t)m * 4 + 3];

  const float* prev = out;
  float*       cur  = out + kM;

  for (int t = 0; ; ) {
    // ---- pre-spin region (compiler drains prev store + prefetch here) ----
    float s[16]; SIG16(s, l0, l1, l2, l3);
    const float* A0 = &prev[idx.x];
    const float* A1 = &prev[idx.y];
    const float* A2 = &prev[idx.z];
    const float* A3 = &prev[idx.w];
    float* const dst = &cur[m];
    __builtin_amdgcn_sched_barrier(0);   // pin: nothing sinks into the spin

    // ---- staggered spin, per-lane early publish ----
    float pA0, pA1, pA2, pA3, pB0, pB1, pB2, pB3;
    POLL_ISSUE4(pA0, pA1, pA2, pA3, A0, A1, A2, A3);
    __builtin_amdgcn_s_sleep(8);         // ~213ns: offset batches by ~RTT/2
    POLL_ISSUE4(pB0, pB1, pB2, pB3, A0, A1, A2, A3);
    bool done = false;
    int tries = 0;
    for (;;) {
      // batch A retired (vmcnt(4) leaves exactly the newest 4 outstanding;
      // any interleaved publish-store is swept up in the same wait)
      asm volatile("s_waitcnt vmcnt(4)" ::: "memory");
      __builtin_amdgcn_sched_barrier(0);
      {
        bool newly = !done & (pA0 >= 0.f) & (pA1 >= 0.f) & (pA2 >= 0.f) & (pA3 >= 0.f);
        if (newly) {   // divergent: newly-ready lanes publish IMMEDIATELY
          done = true;
          agent_store(dst, combine16(s, pA0, pA1, pA2, pA3));
        }
      }
      if (__all(done)) break;
      POLL_ISSUE4(pA0, pA1, pA2, pA3, A0, A1, A2, A3);

      asm volatile("s_waitcnt vmcnt(4)" ::: "memory");
      __builtin_amdgcn_sched_barrier(0);
      {
        bool newly = !done & (pB0 >= 0.f) & (pB1 >= 0.f) & (pB2 >= 0.f) & (pB3 >= 0.f);
        if (newly) {
          done = true;
          agent_store(dst, combine16(s, pB0, pB1, pB2, pB3));
        }
      }
      if (__all(done)) break;
      if (++tries > 512) {
        // escalation valve: drain manual queue, proven compiler-load loop
        asm volatile("s_waitcnt vmcnt(0)" ::: "memory");
        __builtin_amdgcn_sched_barrier(0);
        while (!__all(done)) {
          float q0 = agent_load(A0), q1 = agent_load(A1);
          float q2 = agent_load(A2), q3 = agent_load(A3);
          bool newly = !done & (q0 >= 0.f) & (q1 >= 0.f) & (q2 >= 0.f) & (q3 >= 0.f);
          if (newly) {
            done = true;
            agent_store(dst, combine16(s, q0, q1, q2, q3));
          }
        }
        break;
      }
      POLL_ISSUE4(pB0, pB1, pB2, pB3, A0, A1, A2, A3);
    }
    __builtin_amdgcn_sched_barrier(0);

    // ---- prefetch next layer's statics (aged a full link by use) ----
    const int tn = (t + 1 < kLayers) ? t + 1 : t;   // clamp: harmless reload
    const size_t bn = (size_t)tn * kM + m;
    int4   idxn = pidx[bn];
    float4 n0 = lg[bn * 4 + 0], n1 = lg[bn * 4 + 1];
    float4 n2 = lg[bn * 4 + 2], n3 = lg[bn * 4 + 3];

    if (++t == kLayers) break;
    prev = cur;
    cur += kM;
    idx = idxn;
    l0 = n0; l1 = n1; l2 = n2; l3 = n3;
  }
}

extern "C" void kernel_launch(void* const* d_in, const int* in_sizes, int n_in,
                              void* d_out, int out_size, void* d_ws, size_t ws_size,
                              hipStream_t stream) {
  const float* root = (const float*)d_in[0];
  const float* lg   = (const float*)d_in[1];
  const int*   pidx = (const int*)d_in[2];
  float* out        = (float*)d_out;

  // (kLayers+1)*kM floats = 262144 float4 -> sentinel every launch
  // (harness poisons d_out once but never between graph replays; stale
  // positive values from the previous replay would be read as ready).
  init_sentinel_kernel<<<1024, 256, 0, stream>>>((float4*)out);

  bayes_chain_kernel<<<kBlocks, kThreads, 0, stream>>>(root, lg, pidx, out);
}

// Round 15
// 92.987 us; speedup vs baseline: 19.5548x; 1.0649x over previous
//
#include <hip/hip_runtime.h>
#include <stdint.h>

// Layered Bayesian net marginal chain: 63 sequential layers, M=16384 nodes,
// K=4 parents, C=16 CPT entries per node.
//
// Structure (R5->R10, best=99us, PASSED): global fine-grained dataflow.
// Marginals are strictly positive, so the DATA is its own ready-flag:
// sentinel-init rows, relaxed AGENT-scope write-through stores, consumers
// poll their own 4 parent slots (inline-asm sc0 sc1 loads, hand-placed
// vmcnt(4), staggered batches, per-lane early publish inside the spin).
// No barriers, no fences.
//
// R11 post-mortem: all-manual statics (asm dwordx4 into double-buffered reg
// structs) FAILED correctness (absmax 0.8) — asm-output registers with
// in-flight loads cannot be liveness-protected reliably at this register
// pressure; allocator spill/recycle of an in-flight destination = garbage.
// Reverted: ALL R10 sync machinery byte-identical.
//
// R12: same theory (compiler's pre-SIG16 waitcnt drains a fresh HBM statics
// fetch ~0.5us/layer), safe mechanism: statics prefetch TWO layers deep
// with ordinary compiler loads. Statics for layer t+2 issue post-spin of
// body t; the NEXT body's spin vmcnt(4) (waits until <=4 outstanding)
// hardware-retires them during the wait; consumption at body t+2 then only
// drains the 4 leftover poll loads (~200ns) instead of a fresh HBM fetch.
// Compiler keeps full ownership of statics waits -> R10-grade correctness.

namespace {
constexpr int kLayers  = 63;      // hidden layers
constexpr int kM       = 16384;   // nodes per layer
constexpr int kBlocks  = 256;     // 1 block (1 wave) per CU
constexpr int kThreads = 64;      // kBlocks*kThreads == kM, 1 thread per node
constexpr float kSentinel = -1.0f;
}

// Re-init the whole out buffer (rows 0..63) to sentinel each launch.
// Normal cached stores; kernel-end writeback makes them visible to the
// chain kernel's agent-scope (cache-bypassing) polls.
__global__ void init_sentinel_kernel(float4* __restrict__ out4) {
  int i = blockIdx.x * blockDim.x + threadIdx.x;   // 262144 float4 total
  out4[i] = make_float4(kSentinel, kSentinel, kSentinel, kSentinel);
}

__device__ __forceinline__ float fsig(float x) {
  // sigmoid; fp32 fast-math is far inside the 1.8e-2 abs threshold
  return __fdividef(1.0f, 1.0f + __expf(-x));
}

// Agent-scope (device-coherent) accesses: bypass the non-coherent per-XCD
// L1/L2, hit the coherence point directly. No cache-wide maintenance.
__device__ __forceinline__ void agent_store(float* p, float v) {
  __hip_atomic_store(p, v, __ATOMIC_RELAXED, __HIP_MEMORY_SCOPE_AGENT);
}
__device__ __forceinline__ float agent_load(const float* p) {
  return __hip_atomic_load(p, __ATOMIC_RELAXED, __HIP_MEMORY_SCOPE_AGENT);
}

// Issue 4 agent read-through polls as raw asm: WE own the waitcnt (the
// compiler cannot see these), giving exact control of check cadence.
#define POLL_ISSUE4(r0, r1, r2, r3, A0, A1, A2, A3)                         \
  asm volatile("global_load_dword %0, %4, off sc0 sc1\n\t"                  \
               "global_load_dword %1, %5, off sc0 sc1\n\t"                  \
               "global_load_dword %2, %6, off sc0 sc1\n\t"                  \
               "global_load_dword %3, %7, off sc0 sc1"                      \
               : "=&v"(r0), "=&v"(r1), "=&v"(r2), "=&v"(r3)                 \
               : "v"(A0), "v"(A1), "v"(A2), "v"(A3)                         \
               : "memory")

// weight[c] factorizes over parents (MSB-first bit order, matches _configs):
// c = b0 b1 b2 b3, fk(1)=pk, fk(0)=1-pk.
__device__ __forceinline__ float combine16(const float* s,
                                           float p0, float p1, float p2, float p3) {
  float q0 = 1.0f - p0, q1 = 1.0f - p1, q2 = 1.0f - p2, q3 = 1.0f - p3;
  float w0 = q2 * q3, w1 = q2 * p3, w2 = p2 * q3, w3 = p2 * p3;   // (b2,b3)
  float i0 = s[0]  * w0 + s[1]  * w1 + s[2]  * w2 + s[3]  * w3;   // (b0,b1)=(0,0)
  float i1 = s[4]  * w0 + s[5]  * w1 + s[6]  * w2 + s[7]  * w3;   // (0,1)
  float i2 = s[8]  * w0 + s[9]  * w1 + s[10] * w2 + s[11] * w3;   // (1,0)
  float i3 = s[12] * w0 + s[13] * w1 + s[14] * w2 + s[15] * w3;   // (1,1)
  return (q0 * q1) * i0 + (q0 * p1) * i1 + (p0 * q1) * i2 + (p0 * p1) * i3;
}

#define SIG16(S, V0, V1, V2, V3)                                              \
  S[0]  = fsig((V0).x); S[1]  = fsig((V0).y); S[2]  = fsig((V0).z); S[3]  = fsig((V0).w); \
  S[4]  = fsig((V1).x); S[5]  = fsig((V1).y); S[6]  = fsig((V1).z); S[7]  = fsig((V1).w); \
  S[8]  = fsig((V2).x); S[9]  = fsig((V2).y); S[10] = fsig((V2).z); S[11] = fsig((V2).w); \
  S[12] = fsig((V3).x); S[13] = fsig((V3).y); S[14] = fsig((V3).z); S[15] = fsig((V3).w)

// One layer body. Consumes statics (IDX, L0..L3) for layer t (loaded two
// bodies ago, HW-retired by the intervening spin's vmcnt(4)); spin is the
// exact R10-passing code; post-spin refills the SAME buffer with layer
// t+2's statics via ordinary compiler loads.
#define CHAIN_BODY(IDX, L0, L1, L2, L3)                                      \
  {                                                                          \
    /* pre-spin: compiler's counted wait here only drains ~4 leftover    */ \
    /* polls (~200ns); the statics themselves retired during last spin.  */ \
    float s[16]; SIG16(s, L0, L1, L2, L3);                                   \
    const float* A0 = &prev[(IDX).x];                                        \
    const float* A1 = &prev[(IDX).y];                                        \
    const float* A2 = &prev[(IDX).z];                                        \
    const float* A3 = &prev[(IDX).w];                                        \
    float* const dst = &cur[m];                                              \
    __builtin_amdgcn_sched_barrier(0);                                       \
    /* ---- staggered spin, per-lane early publish (R10, unchanged) ---- */ \
    float pA0, pA1, pA2, pA3, pB0, pB1, pB2, pB3;                            \
    POLL_ISSUE4(pA0, pA1, pA2, pA3, A0, A1, A2, A3);                         \
    __builtin_amdgcn_s_sleep(8);       /* ~213ns: offset batches ~RTT/2 */   \
    POLL_ISSUE4(pB0, pB1, pB2, pB3, A0, A1, A2, A3);                         \
    bool done = false;                                                       \
    int tries = 0;                                                           \
    for (;;) {                                                               \
      /* vmcnt(4): leaves exactly the newest 4 outstanding; retires the */  \
      /* checked batch AND everything older (leftovers, statics, store) */  \
      asm volatile("s_waitcnt vmcnt(4)" ::: "memory");                       \
      __builtin_amdgcn_sched_barrier(0);                                     \
      {                                                                      \
        bool newly = !done & (pA0 >= 0.f) & (pA1 >= 0.f) & (pA2 >= 0.f) & (pA3 >= 0.f); \
        if (newly) {  /* divergent: newly-ready lanes publish NOW */         \
          done = true;                                                       \
          agent_store(dst, combine16(s, pA0, pA1, pA2, pA3));                \
        }                                                                    \
      }                                                                      \
      if (__all(done)) break;                                                \
      POLL_ISSUE4(pA0, pA1, pA2, pA3, A0, A1, A2, A3);                       \
      asm volatile("s_waitcnt vmcnt(4)" ::: "memory");                       \
      __builtin_amdgcn_sched_barrier(0);                                     \
      {                                                                      \
        bool newly = !done & (pB0 >= 0.f) & (pB1 >= 0.f) & (pB2 >= 0.f) & (pB3 >= 0.f); \
        if (newly) {                                                         \
          done = true;                                                       \
          agent_store(dst, combine16(s, pB0, pB1, pB2, pB3));                \
        }                                                                    \
      }                                                                      \
      if (__all(done)) break;                                                \
      if (++tries > 512) {                                                   \
        /* escalation valve: drain manual queue, proven compiler loads */    \
        asm volatile("s_waitcnt vmcnt(0)" ::: "memory");                     \
        __builtin_amdgcn_sched_barrier(0);                                   \
        while (!__all(done)) {                                               \
          float x0 = agent_load(A0), x1 = agent_load(A1);                    \
          float x2 = agent_load(A2), x3 = agent_load(A3);                    \
          bool newly = !done & (x0 >= 0.f) & (x1 >= 0.f) & (x2 >= 0.f) & (x3 >= 0.f); \
          if (newly) {                                                       \
            done = true;                                                     \
            agent_store(dst, combine16(s, x0, x1, x2, x3));                  \
          }                                                                  \
        }                                                                    \
        break;                                                               \
      }                                                                      \
      POLL_ISSUE4(pB0, pB1, pB2, pB3, A0, A1, A2, A3);                       \
    }                                                                        \
    __builtin_amdgcn_sched_barrier(0);                                       \
    /* ---- post-spin: refill this buffer with layer t+2's statics via  */  \
    /* ordinary compiler loads (in flight across the next spin, which   */  \
    /* hardware-retires them; compiler owns the consumption wait).      */  \
    {                                                                        \
      const int tpp = (t + 2 <= kLayers - 1) ? (t + 2) : (kLayers - 1);      \
      const size_t bn = (size_t)tpp * kM + m;                                \
      (IDX) = pidx[bn];                                                      \
      (L0) = lg[bn * 4 + 0]; (L1) = lg[bn * 4 + 1];                          \
      (L2) = lg[bn * 4 + 2]; (L3) = lg[bn * 4 + 3];                          \
    }                                                                        \
    prev = cur;                                                              \
    cur += kM;                                                               \
  }

__global__ __launch_bounds__(kThreads, 1) void bayes_chain_kernel(
    const float* __restrict__ root_logits,   // [kM]
    const float* __restrict__ layer_logits,  // [kLayers][kM][16]
    const int*   __restrict__ parent_idx,    // [kLayers][kM][4]
    float* __restrict__ out)                 // [kLayers+1][kM]
{
  const int m = blockIdx.x * kThreads + threadIdx.x;

  const int4*   pidx = reinterpret_cast<const int4*>(parent_idx);     // [63][M]
  const float4* lg   = reinterpret_cast<const float4*>(layer_logits); // [63][M][4]

  // ---- row 0: root marginals, write-through so consumers' polls see them ----
  agent_store(&out[m], fsig(root_logits[m]));

  // 2-deep statics pipeline: buffer A = layer 0, buffer B = layer 1
  // (compiler loads; no asm polls outstanding yet, waits here are clean).
  int4   idxA = pidx[m];
  float4 la0 = lg[(size_t)m * 4 + 0], la1 = lg[(size_t)m * 4 + 1];
  float4 la2 = lg[(size_t)m * 4 + 2], la3 = lg[(size_t)m * 4 + 3];
  const size_t b1 = (size_t)kM + m;
  int4   idxB = pidx[b1];
  float4 lb0 = lg[b1 * 4 + 0], lb1 = lg[b1 * 4 + 1];
  float4 lb2 = lg[b1 * 4 + 2], lb3 = lg[b1 * 4 + 3];

  const float* prev = out;
  float*       cur  = out + kM;

  int t = 0;
  for (;;) {
    CHAIN_BODY(idxA, la0, la1, la2, la3);   // even layers consume/refill A
    if (++t == kLayers) break;
    CHAIN_BODY(idxB, lb0, lb1, lb2, lb3);   // odd layers consume/refill B
    if (++t == kLayers) break;
  }
}

extern "C" void kernel_launch(void* const* d_in, const int* in_sizes, int n_in,
                              void* d_out, int out_size, void* d_ws, size_t ws_size,
                              hipStream_t stream) {
  const float* root = (const float*)d_in[0];
  const float* lg   = (const float*)d_in[1];
  const int*   pidx = (const int*)d_in[2];
  float* out        = (float*)d_out;

  // (kLayers+1)*kM floats = 262144 float4 -> sentinel every launch
  // (harness poisons d_out once but never between graph replays; stale
  // positive values from the previous replay would be read as ready).
  init_sentinel_kernel<<<1024, 256, 0, stream>>>((float4*)out);

  bayes_chain_kernel<<<kBlocks, kThreads, 0, stream>>>(root, lg, pidx, out);
}